// Round 8
// baseline (505.878 us; speedup 1.0000x reference)
//
#include <hip/hip_runtime.h>
#include <hip/hip_bf16.h>

#define BB   128
#define TT   256
#define CC   384
#define HH   6
#define HSZ  64
#define DFF  1536
#define EPSV 1e-5f
#define RPB  8
#define NTOK (BB * TT)          // 32768
#define NQKV (3 * CC)           // 1152

typedef __attribute__((ext_vector_type(8))) short  short8;
typedef __attribute__((ext_vector_type(4))) float  f32x4;
typedef __hip_bfloat16 bf16;

#define WAITV(n) asm volatile("s_waitcnt vmcnt(" #n ")" ::: "memory")
#define WAITL    asm volatile("s_waitcnt lgkmcnt(0)" ::: "memory")
#define BAR      __builtin_amdgcn_s_barrier()
#define SCHED    __builtin_amdgcn_sched_barrier(0)

// async 16B global -> LDS (lane-contiguous at wave-uniform base)
__device__ __forceinline__ void async_copy16(const bf16* g, bf16* l) {
    __builtin_amdgcn_global_load_lds(
        (const __attribute__((address_space(1))) void*)g,
        (__attribute__((address_space(3))) void*)l, 16, 0, 0);
}

// ---------------- block-wide reduction over 384 threads (6 waves) -------------
__device__ __forceinline__ void block_reduce2(float& a, float& b, float* red) {
    #pragma unroll
    for (int off = 32; off > 0; off >>= 1) {
        a += __shfl_down(a, off, 64);
        b += __shfl_down(b, off, 64);
    }
    const int lane = threadIdx.x & 63;
    const int wid  = threadIdx.x >> 6;
    if (lane == 0) { red[wid * 2] = a; red[wid * 2 + 1] = b; }
    __syncthreads();
    if (threadIdx.x == 0) {
        float sa = 0.f, sb = 0.f;
        #pragma unroll
        for (int w = 0; w < 6; ++w) { sa += red[w * 2]; sb += red[w * 2 + 1]; }
        red[12] = sa; red[13] = sb;
    }
    __syncthreads();
    a = red[12]; b = red[13];
}

// ---------------- LN -> bf16 --------------------------------------------------
__global__ __launch_bounds__(CC) void ln_bf16_kernel(
        const float* __restrict__ x, const float* __restrict__ g,
        const float* __restrict__ be, bf16* __restrict__ y) {
    __shared__ float red[16];
    const int tid = threadIdx.x;
    const long row0 = (long)blockIdx.x * RPB;
    const float gg = g[tid], bb = be[tid];
    for (int r = 0; r < RPB; ++r) {
        float v = x[(row0 + r) * CC + tid];
        float s = v, sq = v * v;
        block_reduce2(s, sq, red);
        float mu  = s  * (1.0f / CC);
        float var = sq * (1.0f / CC) - mu * mu;
        float rs  = rsqrtf(var + EPSV);
        y[(row0 + r) * CC + tid] = __float2bfloat16((v - mu) * rs * gg + bb);
        __syncthreads();
    }
}

// ---------------- unified weight packing (all transposes in ONE launch) -------
__global__ __launch_bounds__(256) void pack_weights(
        const float* __restrict__ Wq, const float* __restrict__ Wk,
        const float* __restrict__ Wv, const float* __restrict__ Wo,
        const float* __restrict__ W1, const float* __restrict__ W2,
        bf16* __restrict__ WcatT, bf16* __restrict__ WoT,
        bf16* __restrict__ W1T, bf16* __restrict__ W2T) {
    __shared__ float t[32][33];
    const int id = blockIdx.x;
    const float* in; bf16* out; int R, Cn, c0, r0;
    if (id < 432) {
        const int which = id / 144, rem = id % 144, h = rem / 24, tt = rem % 24;
        const float* W = (which == 0) ? Wq : ((which == 1) ? Wk : Wv);
        in = W + (long)h * CC * HSZ;  R = CC; Cn = HSZ;
        c0 = (tt % 2) * 32; r0 = (tt / 2) * 32;
        out = WcatT + ((long)which * CC + h * HSZ) * CC;
    } else if (id < 576) {
        const int i2 = id - 432;
        in = Wo; out = WoT; R = CC; Cn = CC;
        c0 = (i2 % 12) * 32; r0 = (i2 / 12) * 32;
    } else if (id < 1152) {
        const int i3 = id - 576;
        in = W1; out = W1T; R = CC; Cn = DFF;
        c0 = (i3 % 48) * 32; r0 = (i3 / 48) * 32;
    } else {
        const int i4 = id - 1152;
        in = W2; out = W2T; R = DFF; Cn = CC;
        c0 = (i4 % 12) * 32; r0 = (i4 / 12) * 32;
    }
    const int tid = threadIdx.x, tx = tid & 31, ty = tid >> 5;
    #pragma unroll
    for (int p = 0; p < 4; ++p)
        t[ty + p * 8][tx] = in[(long)(r0 + ty + p * 8) * Cn + c0 + tx];
    __syncthreads();
    #pragma unroll
    for (int p = 0; p < 4; ++p)
        out[(long)(c0 + ty + p * 8) * R + r0 + tx] = __float2bfloat16(t[tx][ty + p * 8]);
}

// ---------------- MFMA GEMM 128x384 full-N panel (QKV / Wo) -------------------
template<int K, int EPI>
__global__ __launch_bounds__(512) void gemm_fn(
        const bf16* __restrict__ A, const bf16* __restrict__ BT,
        const float* __restrict__ bias, const float* __restrict__ res,
        float* __restrict__ outF, bf16* __restrict__ outB, int N, int nby) {
    __shared__ bf16 A0[128 * 32];
    __shared__ bf16 A1[128 * 32];
    __shared__ bf16 B0[384 * 32];
    __shared__ bf16 B1[384 * 32];

    const int tid = threadIdx.x;
    const int hwid  = blockIdx.x;
    const int chunk = gridDim.x >> 3;
    const int e     = hwid & 7;
    const int s     = hwid >> 3;
    const int gx    = chunk / nby;
    const int bx    = e * gx + s / nby;
    const int by    = s - (s / nby) * nby;
    const int m0 = bx * 128;
    const int n0 = by * 384;

    const int ln   = tid & 63;
    const int wid  = tid >> 6;
    const int wm   = (wid & 1) * 64;
    const int wn   = (wid >> 1) * 96;
    const int fr   = ln & 15;
    const int quad = ln >> 4;
    const int slot = quad ^ ((fr >> 1) & 3);

    const int rA = tid >> 2, gA = (tid & 3) ^ ((rA >> 1) & 3);
    const long gaA = (long)rA * K + gA * 8;
    const int uB1 = tid + 512, uB2 = tid + 1024;
    const int rB0 = tid >> 2, gB0 = (tid & 3) ^ ((rB0 >> 1) & 3);
    const int rB1 = uB1 >> 2, gB1 = (uB1 & 3) ^ ((rB1 >> 1) & 3);
    const int rB2 = uB2 >> 2, gB2 = (uB2 & 3) ^ ((rB2 >> 1) & 3);
    const long gaB0 = (long)rB0 * K + gB0 * 8;
    const long gaB1 = (long)rB1 * K + gB1 * 8;
    const long gaB2 = (long)rB2 * K + gB2 * 8;
    const bf16* Ap  = A  + (long)m0 * K;
    const bf16* BTp = BT + (long)n0 * K;

    f32x4 acc[4][6];
    #pragma unroll
    for (int i = 0; i < 4; ++i)
        #pragma unroll
        for (int j = 0; j < 6; ++j)
            acc[i][j] = (f32x4){0.f, 0.f, 0.f, 0.f};

    constexpr int NT = K / 32;

    auto stage = [&](long k0, bf16* Ad, bf16* Bd) {
        async_copy16(Ap  + gaA  + k0, Ad + tid * 8);
        async_copy16(BTp + gaB0 + k0, Bd + tid * 8);
        async_copy16(BTp + gaB1 + k0, Bd + uB1 * 8);
        async_copy16(BTp + gaB2 + k0, Bd + uB2 * 8);
    };

    auto phase = [&](int t, bf16* Ab, bf16* Bb) {
        if (t + 1 < NT) { WAITV(4); } else { WAITV(0); }
        BAR;
        short8 af[4], bfr[6];
        #pragma unroll
        for (int i = 0; i < 4; ++i)
            af[i] = *(const short8*)(Ab + (wm + i * 16 + fr) * 32 + slot * 8);
        #pragma unroll
        for (int j = 0; j < 6; ++j)
            bfr[j] = *(const short8*)(Bb + (wn + j * 16 + fr) * 32 + slot * 8);
        WAITL;
        BAR;
        SCHED;
        if (t + 2 < NT) stage((long)(t + 2) * 32, Ab, Bb);
        #pragma unroll
        for (int i = 0; i < 4; ++i)
            #pragma unroll
            for (int j = 0; j < 6; ++j)
                acc[i][j] = __builtin_amdgcn_mfma_f32_16x16x32_bf16(
                    af[i], bfr[j], acc[i][j], 0, 0, 0);
    };

    stage(0,  A0, B0);
    stage(32, A1, B1);

    for (int t = 0; t < NT; t += 2) {
        phase(t,     A0, B0);
        phase(t + 1, A1, B1);
    }

    #pragma unroll
    for (int i = 0; i < 4; ++i) {
        #pragma unroll
        for (int j = 0; j < 6; ++j) {
            const int col = n0 + wn + j * 16 + fr;
            #pragma unroll
            for (int r = 0; r < 4; ++r) {
                const int row = m0 + wm + i * 16 + quad * 4 + r;
                const long idx = (long)row * N + col;
                float v = acc[i][j][r];
                if (EPI == 2) {
                    outF[idx] = v + bias[col] + res[idx];
                } else {
                    outB[idx] = __float2bfloat16(v);
                }
            }
        }
    }
}

// ---------------- FUSED FFN: out += relu(actb @ W1 + b1) @ W2 + b2 ------------
// Grid 256 (1 block/CU), 512 thr. Loop 8 DFF-chunks of 192:
//   GEMM1 (K=384, BK=64, 6 phases): acc1 = A @ W1T_chunk^T; relu+bias -> bf16
//   -> P-LDS (lane-pair packed b32 writes, slot-swizzled [6][128][32]);
//   GEMM2 (K=192 chunk, BK=32, 6 phases): acc2 += P @ W2T_chunk^T.
// Stage modes are EXPLICIT per phase (R7 bug: Bstg=nullptr corrupted Pl):
//   mode 0 = stage G1 tile (A step aux -> AD, W1T chunk dffm step aux -> BD)
//   mode 1 = stage B2 tile (W2T chunk dffm K-step aux -> BD)
//   mode 2 = none
// In-flight ledger (loads/thread): G1 stage = 5 (A2+B3), B2 stage = 3.
// Steady state: 10 during G1 phases 0-3, 8/6 at G1p4/5, 6 during G2p0-3,
// 8/10 at G2p4/5 (next-chunk G1 prefetch). Waits 5/3 pick exactly the
// intended oldest batch; vmcnt drains to 0 only in the last chunk.
__global__ __launch_bounds__(512, 1) void ffn_fused(
        const bf16* __restrict__ A, const bf16* __restrict__ W1T,
        const bf16* __restrict__ W2T, const float* __restrict__ b1,
        const float* __restrict__ b2, float* __restrict__ out) {
    __shared__ bf16 Pl[6 * 128 * 32];        // 49152 B
    __shared__ bf16 Ab0[2 * 128 * 32];       // 8192 B each buf... [2][128][32]
    __shared__ bf16 Ab1[2 * 128 * 32];
    __shared__ bf16 Bb0[1536 * 8];           // 24576 B
    __shared__ bf16 Bb1[1536 * 8];
    __shared__ float b1L[DFF];
    __shared__ float b2L[CC];

    const int tid  = threadIdx.x;
    const int hwid = blockIdx.x;
    const int bx   = (hwid & 7) * 32 + (hwid >> 3);   // XCD-chunked, grid 256
    const int m0   = bx * 128;

    const int ln   = tid & 63;
    const int wid  = tid >> 6;
    const int wm   = (wid & 1) * 64;
    const int wn1  = (wid >> 1) * 48;    // GEMM1 N-quarter (192/4)
    const int wn2  = (wid >> 1) * 96;    // GEMM2 N-quarter (384/4)
    const int fr   = ln & 15;
    const int quad = ln >> 4;
    const int sw8  = (quad ^ ((fr >> 1) & 3)) * 8;

    for (int t = tid; t < DFF; t += 512) b1L[t] = b1[t];
    for (int t = tid; t < CC;  t += 512) b2L[t] = b2[t];

    const bf16* Ap = A + (long)m0 * CC;

    // stage A step s (BK=64, [2][128][32] subtiles), 2 loads/thread
    auto stageA = [&](int s, bf16* Ad) {
        #pragma unroll
        for (int p = 0; p < 2; ++p) {
            const int u = tid + p * 512;
            const int kk = u >> 9, idx = u & 511;
            const int row = idx >> 2, g = idx & 3;
            const int gg = g ^ ((row >> 1) & 3);
            async_copy16(Ap + (long)row * CC + s * 64 + kk * 32 + gg * 8,
                         Ad + u * 8);
        }
    };
    // stage W1T chunk dffm, K-step s (BK=64, [2][192][32]), 3 loads/thread
    auto stageB1 = [&](int dffm, int s, bf16* Bd) {
        #pragma unroll
        for (int p = 0; p < 3; ++p) {
            const int u = tid + p * 512;
            const int sub = (u >= 768) ? 1 : 0;
            const int idx = u - sub * 768;
            const int row = idx >> 2, g = idx & 3;
            const int gg = g ^ ((row >> 1) & 3);
            async_copy16(W1T + (long)(dffm + row) * CC + s * 64 + sub * 32 + gg * 8,
                         Bd + u * 8);
        }
    };
    // stage W2T chunk dffm, K-step uu (BK=32, [384][32]), 3 loads/thread
    auto stageB2 = [&](int dffm, int uu, bf16* Bd) {
        #pragma unroll
        for (int p = 0; p < 3; ++p) {
            const int u = tid + p * 512;
            const int row = u >> 2, g = u & 3;
            const int gg = g ^ ((row >> 1) & 3);
            async_copy16(W2T + (long)row * DFF + dffm + uu * 32 + gg * 8,
                         Bd + u * 8);
        }
    };

    f32x4 acc1[4][3], acc2[4][6];
    #pragma unroll
    for (int i = 0; i < 4; ++i) {
        #pragma unroll
        for (int j = 0; j < 3; ++j) acc1[i][j] = (f32x4){0.f, 0.f, 0.f, 0.f};
        #pragma unroll
        for (int j = 0; j < 6; ++j) acc2[i][j] = (f32x4){0.f, 0.f, 0.f, 0.f};
    }

    // GEMM1 phase body (call after WAITV+BAR). mode/aux/dffm as documented.
    auto g1phase = [&](const bf16* Ac, const bf16* Bc, int mode, int dffm,
                       int aux, bf16* AD, bf16* BD) {
        short8 af[4][2], bf1[3][2];
        #pragma unroll
        for (int kk = 0; kk < 2; ++kk) {
            #pragma unroll
            for (int i = 0; i < 4; ++i)
                af[i][kk] = *(const short8*)(Ac + ((kk << 7) + wm + i * 16 + fr) * 32 + sw8);
            #pragma unroll
            for (int j = 0; j < 3; ++j)
                bf1[j][kk] = *(const short8*)(Bc + (kk * 192 + wn1 + j * 16 + fr) * 32 + sw8);
        }
        WAITL;
        BAR;
        SCHED;
        if (mode == 0) { stageA(aux, AD); stageB1(dffm, aux, BD); }
        else if (mode == 1) { stageB2(dffm, aux, BD); }
        #pragma unroll
        for (int kk = 0; kk < 2; ++kk)
            #pragma unroll
            for (int i = 0; i < 4; ++i)
                #pragma unroll
                for (int j = 0; j < 3; ++j)
                    acc1[i][j] = __builtin_amdgcn_mfma_f32_16x16x32_bf16(
                        af[i][kk], bf1[j][kk], acc1[i][j], 0, 0, 0);
    };
    // GEMM2 phase body
    auto g2phase = [&](int uu, const bf16* Bc, int mode, int dffm,
                       int aux, bf16* AD, bf16* BD) {
        short8 af2[4], bf2[6];
        #pragma unroll
        for (int i = 0; i < 4; ++i)
            af2[i] = *(const short8*)(Pl + (uu * 128 + wm + i * 16 + fr) * 32 + sw8);
        #pragma unroll
        for (int j = 0; j < 6; ++j)
            bf2[j] = *(const short8*)(Bc + (wn2 + j * 16 + fr) * 32 + sw8);
        WAITL;
        BAR;
        SCHED;
        if (mode == 0) { stageA(aux, AD); stageB1(dffm, aux, BD); }
        else if (mode == 1) { stageB2(dffm, aux, BD); }
        #pragma unroll
        for (int i = 0; i < 4; ++i)
            #pragma unroll
            for (int j = 0; j < 6; ++j)
                acc2[i][j] = __builtin_amdgcn_mfma_f32_16x16x32_bf16(
                    af2[i], bf2[j], acc2[i][j], 0, 0, 0);
    };

    __syncthreads();   // bias preload visible; vmcnt drained -> clean ledger

    // prologue: chunk 0, G1 tiles s0,s1 -> 10 loads/thread in flight
    stageA(0, Ab0); stageB1(0, 0, Bb0);
    stageA(1, Ab1); stageB1(0, 1, Bb1);

    for (int cc = 0; cc < 8; ++cc) {
        const int dff0 = cc * 192;
        const bool pf  = (cc < 7);
        const int dffN = dff0 + 192;

        // ---- GEMM1: 6 phases (BK=64) ----
        WAITV(5); BAR; g1phase(Ab0, Bb0, 0, dff0, 2, Ab0, Bb0);
        WAITV(5); BAR; g1phase(Ab1, Bb1, 0, dff0, 3, Ab1, Bb1);
        WAITV(5); BAR; g1phase(Ab0, Bb0, 0, dff0, 4, Ab0, Bb0);
        WAITV(5); BAR; g1phase(Ab1, Bb1, 0, dff0, 5, Ab1, Bb1);
        WAITV(5); BAR; g1phase(Ab0, Bb0, 1, dff0, 0, nullptr, Bb0);
        WAITV(3); BAR; g1phase(Ab1, Bb1, 1, dff0, 1, nullptr, Bb1);

        // ---- P phase: relu(acc1+b1) -> bf16 pair-packed -> P-LDS ----
        #pragma unroll
        for (int j = 0; j < 3; ++j) {
            const float b1v = b1L[dff0 + wn1 + j * 16 + fr];
            #pragma unroll
            for (int i = 0; i < 4; ++i) {
                #pragma unroll
                for (int r = 0; r < 4; ++r) {
                    const float v = fmaxf(acc1[i][j][r] + b1v, 0.f);
                    const float pv = __shfl_xor(v, 1, 64);
                    if (!(ln & 1)) {
                        __hip_bfloat16 hl = __float2bfloat16(v);
                        __hip_bfloat16 hh = __float2bfloat16(pv);
                        const unsigned word =
                            (unsigned)*(unsigned short*)&hl |
                            ((unsigned)*(unsigned short*)&hh << 16);
                        const int colC = wn1 + j * 16 + fr;      // even
                        const int row  = wm + i * 16 + quad * 4 + r;
                        const int kt = colC >> 5, cl = colC & 31;
                        const int phys = ((cl >> 3) ^ ((row >> 1) & 3)) * 8 + (cl & 7);
                        *(unsigned*)((char*)Pl + ((kt * 128 + row) * 32 + phys) * 2) = word;
                    }
                    acc1[i][j][r] = 0.f;
                }
            }
        }
        WAITL;   // this wave's P ds_writes retired before the next barrier

        // ---- GEMM2: 6 phases (BK=32) ----
        WAITV(3); BAR; g2phase(0, Bb0, 1, dff0, 2, nullptr, Bb0);
        WAITV(3); BAR; g2phase(1, Bb1, 1, dff0, 3, nullptr, Bb1);
        WAITV(3); BAR; g2phase(2, Bb0, 1, dff0, 4, nullptr, Bb0);
        WAITV(3); BAR; g2phase(3, Bb1, 1, dff0, 5, nullptr, Bb1);
        WAITV(3); BAR; g2phase(4, Bb0, pf ? 0 : 2, dffN, 0, Ab0, Bb0);
        if (pf) { WAITV(5); } else { WAITV(0); }
        BAR;           g2phase(5, Bb1, pf ? 0 : 2, dffN, 1, Ab1, Bb1);
    }

    // ---- epilogue: out += acc2 + b2 ----
    #pragma unroll
    for (int i = 0; i < 4; ++i) {
        #pragma unroll
        for (int j = 0; j < 6; ++j) {
            const int col = wn2 + j * 16 + fr;
            const float b2v = b2L[col];
            #pragma unroll
            for (int r = 0; r < 4; ++r) {
                const int row = m0 + wm + i * 16 + quad * 4 + r;
                const long idx = (long)row * CC + col;
                out[idx] = acc2[i][j][r] + b2v + out[idx];
            }
        }
    }
}

// ---------------- MFMA causal flash attention ---------------------------------
struct alignas(8) bh4s { bf16 a, b, c, d; };

__global__ __launch_bounds__(256, 2) void attn_mfma_kernel(
        const bf16* __restrict__ qkv, bf16* __restrict__ ab) {
    __shared__ bf16 Kt[64][72];
    __shared__ bf16 Vt[64][72];
    __shared__ bf16 Pb[4][16][72];

    const int tid  = threadIdx.x;
    const int bh   = blockIdx.x;
    const int b    = bh / HH, h = bh % HH;
    const int w    = tid >> 6;
    const int ln   = tid & 63;
    const int ln15 = ln & 15;
    const int quad = ln >> 4;

    short8 qf[4][2];
    #pragma unroll
    for (int i = 0; i < 4; ++i) {
        const long tok = (long)b * TT + w * 16 + i * 64 + ln15;
        const bf16* p = qkv + tok * NQKV + h * HSZ + quad * 8;
        qf[i][0] = *(const short8*)p;
        qf[i][1] = *(const short8*)(p + 32);
    }

    f32x4 accO[4][4];
    float mrow[4][4], lrow[4][4];
    #pragma unroll
    for (int i = 0; i < 4; ++i) {
        #pragma unroll
        for (int j = 0; j < 4; ++j) accO[i][j] = (f32x4){0.f, 0.f, 0.f, 0.f};
        #pragma unroll
        for (int r = 0; r < 4; ++r) { mrow[i][r] = -1e30f; lrow[i][r] = 0.f; }
    }

    for (int sidx = 0; sidx < 4; ++sidx) {
        const int s0 = sidx * 64;
        __syncthreads();
        {
            const bf16* kg = qkv + (long)(b * TT + s0) * NQKV + CC + h * HSZ;
            #pragma unroll
            for (int it = 0; it < 2; ++it) {
                const int u = tid + it * 256;
                const int r = u >> 3, c = (u & 7) * 8;
                *(uint4*)&Kt[r][c] = *(const uint4*)(kg + (long)r * NQKV + c);
            }
            const bf16* vg = qkv + (long)(b * TT + s0) * NQKV + 2 * CC + h * HSZ;
            const int s = tid & 63;
            #pragma unroll
            for (int it = 0; it < 4; ++it) {
                const int dq = (tid >> 6) + it * 4;
                const bh4s vv = *(const bh4s*)(vg + (long)s * NQKV + dq * 4);
                Vt[dq * 4 + 0][s] = vv.a;
                Vt[dq * 4 + 1][s] = vv.b;
                Vt[dq * 4 + 2][s] = vv.c;
                Vt[dq * 4 + 3][s] = vv.d;
            }
        }
        __syncthreads();

        #pragma unroll
        for (int i = 0; i < 4; ++i) {
            if (i < sidx) continue;        // uniform guard; i stays compile-time
            const int rb = w * 16 + i * 64;
            f32x4 S[4];
            #pragma unroll
            for (int jt = 0; jt < 4; ++jt) S[jt] = (f32x4){0.f, 0.f, 0.f, 0.f};
            #pragma unroll
            for (int ks = 0; ks < 2; ++ks) {
                #pragma unroll
                for (int jt = 0; jt < 4; ++jt) {
                    const short8 kf = *(const short8*)&Kt[jt * 16 + ln15][ks * 32 + quad * 8];
                    S[jt] = __builtin_amdgcn_mfma_f32_16x16x32_bf16(qf[i][ks], kf, S[jt], 0, 0, 0);
                }
            }
            float rmax[4];
            #pragma unroll
            for (int r = 0; r < 4; ++r) rmax[r] = -1e30f;
            #pragma unroll
            for (int jt = 0; jt < 4; ++jt) {
                #pragma unroll
                for (int r = 0; r < 4; ++r) {
                    float v = S[jt][r] * 0.125f;
                    if (i == sidx) {
                        const int col = s0 + jt * 16 + ln15;
                        const int row = rb + quad * 4 + r;
                        if (col > row) v = -1e30f;
                    }
                    S[jt][r] = v;
                    rmax[r] = fmaxf(rmax[r], v);
                }
            }
            #pragma unroll
            for (int off = 1; off < 16; off <<= 1)
                #pragma unroll
                for (int r = 0; r < 4; ++r)
                    rmax[r] = fmaxf(rmax[r], __shfl_xor(rmax[r], off, 64));

            float alpha[4], rsum[4];
            #pragma unroll
            for (int r = 0; r < 4; ++r) {
                const float mn = fmaxf(mrow[i][r], rmax[r]);
                alpha[r] = __expf(mrow[i][r] - mn);
                mrow[i][r] = mn;
                rsum[r] = 0.f;
            }
            #pragma unroll
            for (int jt = 0; jt < 4; ++jt)
                #pragma unroll
                for (int r = 0; r < 4; ++r) {
                    const float p = __expf(S[jt][r] - mrow[i][r]);
                    S[jt][r] = p;
                    rsum[r] += p;
                }
            #pragma unroll
            for (int off = 1; off < 16; off <<= 1)
                #pragma unroll
                for (int r = 0; r < 4; ++r)
                    rsum[r] += __shfl_xor(rsum[r], off, 64);
            #pragma unroll
            for (int r = 0; r < 4; ++r)
                lrow[i][r] = lrow[i][r] * alpha[r] + rsum[r];
            #pragma unroll
            for (int jt = 0; jt < 4; ++jt)
                #pragma unroll
                for (int r = 0; r < 4; ++r)
                    accO[i][jt][r] *= alpha[r];

            #pragma unroll
            for (int jt = 0; jt < 4; ++jt)
                #pragma unroll
                for (int r = 0; r < 4; ++r)
                    Pb[w][quad * 4 + r][jt * 16 + ln15] = __float2bfloat16(S[jt][r]);
            const short8 pf0 = *(const short8*)&Pb[w][ln15][quad * 8];
            const short8 pf1 = *(const short8*)&Pb[w][ln15][32 + quad * 8];
            #pragma unroll
            for (int jt = 0; jt < 4; ++jt) {
                const short8 vf0 = *(const short8*)&Vt[jt * 16 + ln15][quad * 8];
                const short8 vf1 = *(const short8*)&Vt[jt * 16 + ln15][32 + quad * 8];
                accO[i][jt] = __builtin_amdgcn_mfma_f32_16x16x32_bf16(pf0, vf0, accO[i][jt], 0, 0, 0);
                accO[i][jt] = __builtin_amdgcn_mfma_f32_16x16x32_bf16(pf1, vf1, accO[i][jt], 0, 0, 0);
            }
        }
    }

    #pragma unroll
    for (int i = 0; i < 4; ++i) {
        const int rb = w * 16 + i * 64;
        float inv[4];
        #pragma unroll
        for (int r = 0; r < 4; ++r) inv[r] = 1.0f / lrow[i][r];
        #pragma unroll
        for (int jt = 0; jt < 4; ++jt)
            #pragma unroll
            for (int r = 0; r < 4; ++r)
                Pb[w][quad * 4 + r][jt * 16 + ln15] = __float2bfloat16(accO[i][jt][r] * inv[r]);
        #pragma unroll
        for (int it = 0; it < 2; ++it) {
            const int u = ln + it * 64;
            const int row = u >> 3, ch = (u & 7) * 8;
            const long tok = (long)b * TT + rb + row;
            *(uint4*)(ab + tok * CC + h * HSZ + ch) = *(const uint4*)&Pb[w][row][ch];
        }
    }
}

// ---------------- launcher ----------------------------------------------------
extern "C" void kernel_launch(void* const* d_in, const int* in_sizes, int n_in,
                              void* d_out, int out_size, void* d_ws, size_t ws_size,
                              hipStream_t stream) {
    const float* x   = (const float*)d_in[0];
    const float* Wq  = (const float*)d_in[1];
    const float* Wk  = (const float*)d_in[2];
    const float* Wv  = (const float*)d_in[3];
    const float* Wo  = (const float*)d_in[4];
    const float* bo  = (const float*)d_in[5];
    const float* W1  = (const float*)d_in[6];
    const float* b1  = (const float*)d_in[7];
    const float* W2  = (const float*)d_in[8];
    const float* b2  = (const float*)d_in[9];
    const float* g1  = (const float*)d_in[10];
    const float* be1 = (const float*)d_in[11];
    const float* g2  = (const float*)d_in[12];
    const float* be2 = (const float*)d_in[13];

    float* out = (float*)d_out;
    char*  ws  = (char*)d_ws;

    const size_t qkvBytes = (size_t)NTOK * NQKV * 4;
    const size_t actOff   = (qkvBytes + 255) & ~(size_t)255;
    const size_t actBytes = (size_t)NTOK * CC * 2;
    size_t wOff = (actOff + actBytes + 255) & ~(size_t)255;

    bf16* qkvb = (bf16*)ws;
    bf16* actb = (bf16*)(ws + actOff);

    bf16* WcatT = (bf16*)(ws + wOff); wOff += (size_t)NQKV * CC * 2 + 256;
    bf16* WoT   = (bf16*)(ws + ((wOff + 255) & ~(size_t)255)); wOff = ((wOff + 255) & ~(size_t)255) + (size_t)CC * CC * 2;
    bf16* W1T   = (bf16*)(ws + ((wOff + 255) & ~(size_t)255)); wOff = ((wOff + 255) & ~(size_t)255) + (size_t)DFF * CC * 2;
    bf16* W2T   = (bf16*)(ws + ((wOff + 255) & ~(size_t)255));

    pack_weights<<<1728, 256, 0, stream>>>(Wq, Wk, Wv, Wo, W1, W2,
                                           WcatT, WoT, W1T, W2T);

    ln_bf16_kernel<<<NTOK / RPB, CC, 0, stream>>>(x, g1, be1, actb);
    // QKV: M=32768, 3 col-groups of 384 -> grid 768
    gemm_fn<CC, 3><<<(NTOK / 128) * 3, 512, 0, stream>>>(
        actb, WcatT, nullptr, nullptr, nullptr, qkvb, NQKV, 3);
    attn_mfma_kernel<<<BB * HH, 256, 0, stream>>>(qkvb, actb);
    // Wo: 1 col-group -> grid 256 = 1 block/CU
    gemm_fn<CC, 2><<<(NTOK / 128), 512, 0, stream>>>(
        actb, WoT, bo, x, out, nullptr, CC, 1);

    ln_bf16_kernel<<<NTOK / RPB, CC, 0, stream>>>(out, g2, be2, actb);
    // fused FFN: out += relu(actb @ W1 + b1) @ W2 + b2
    ffn_fused<<<256, 512, 0, stream>>>(actb, W1T, W2T, b1, b2, out);
}

// Round 9
// 427.193 us; speedup vs baseline: 1.1842x; 1.1842x over previous
//
#include <hip/hip_runtime.h>
#include <hip/hip_bf16.h>

#define BB   128
#define TT   256
#define CC   384
#define HH   6
#define HSZ  64
#define DFF  1536
#define EPSV 1e-5f
#define RPB  8
#define NTOK (BB * TT)          // 32768
#define NQKV (3 * CC)           // 1152

typedef __attribute__((ext_vector_type(8))) short  short8;
typedef __attribute__((ext_vector_type(4))) float  f32x4;
typedef __hip_bfloat16 bf16;

#define WAITV(n) asm volatile("s_waitcnt vmcnt(" #n ")" ::: "memory")
#define BAR      __builtin_amdgcn_s_barrier()
#define SCHED    __builtin_amdgcn_sched_barrier(0)

// async 16B global -> LDS (lane-contiguous at wave-uniform base)
__device__ __forceinline__ void async_copy16(const bf16* g, bf16* l) {
    __builtin_amdgcn_global_load_lds(
        (const __attribute__((address_space(1))) void*)g,
        (__attribute__((address_space(3))) void*)l, 16, 0, 0);
}

// ---------------- block-wide reduction over 384 threads (6 waves) -------------
__device__ __forceinline__ void block_reduce2(float& a, float& b, float* red) {
    #pragma unroll
    for (int off = 32; off > 0; off >>= 1) {
        a += __shfl_down(a, off, 64);
        b += __shfl_down(b, off, 64);
    }
    const int lane = threadIdx.x & 63;
    const int wid  = threadIdx.x >> 6;
    if (lane == 0) { red[wid * 2] = a; red[wid * 2 + 1] = b; }
    __syncthreads();
    if (threadIdx.x == 0) {
        float sa = 0.f, sb = 0.f;
        #pragma unroll
        for (int w = 0; w < 6; ++w) { sa += red[w * 2]; sb += red[w * 2 + 1]; }
        red[12] = sa; red[13] = sb;
    }
    __syncthreads();
    a = red[12]; b = red[13];
}

// ---------------- LN -> bf16 --------------------------------------------------
__global__ __launch_bounds__(CC) void ln_bf16_kernel(
        const float* __restrict__ x, const float* __restrict__ g,
        const float* __restrict__ be, bf16* __restrict__ y) {
    __shared__ float red[16];
    const int tid = threadIdx.x;
    const long row0 = (long)blockIdx.x * RPB;
    const float gg = g[tid], bb = be[tid];
    for (int r = 0; r < RPB; ++r) {
        float v = x[(row0 + r) * CC + tid];
        float s = v, sq = v * v;
        block_reduce2(s, sq, red);
        float mu  = s  * (1.0f / CC);
        float var = sq * (1.0f / CC) - mu * mu;
        float rs  = rsqrtf(var + EPSV);
        y[(row0 + r) * CC + tid] = __float2bfloat16((v - mu) * rs * gg + bb);
        __syncthreads();
    }
}

// ---------------- unified weight packing (all transposes in ONE launch) -------
__global__ __launch_bounds__(256) void pack_weights(
        const float* __restrict__ Wq, const float* __restrict__ Wk,
        const float* __restrict__ Wv, const float* __restrict__ Wo,
        const float* __restrict__ W1, const float* __restrict__ W2,
        bf16* __restrict__ WcatT, bf16* __restrict__ WoT,
        bf16* __restrict__ W1T, bf16* __restrict__ W2T) {
    __shared__ float t[32][33];
    const int id = blockIdx.x;
    const float* in; bf16* out; int R, Cn, c0, r0;
    if (id < 432) {
        const int which = id / 144, rem = id % 144, h = rem / 24, tt = rem % 24;
        const float* W = (which == 0) ? Wq : ((which == 1) ? Wk : Wv);
        in = W + (long)h * CC * HSZ;  R = CC; Cn = HSZ;
        c0 = (tt % 2) * 32; r0 = (tt / 2) * 32;
        out = WcatT + ((long)which * CC + h * HSZ) * CC;
    } else if (id < 576) {
        const int i2 = id - 432;
        in = Wo; out = WoT; R = CC; Cn = CC;
        c0 = (i2 % 12) * 32; r0 = (i2 / 12) * 32;
    } else if (id < 1152) {
        const int i3 = id - 576;
        in = W1; out = W1T; R = CC; Cn = DFF;
        c0 = (i3 % 48) * 32; r0 = (i3 / 48) * 32;
    } else {
        const int i4 = id - 1152;
        in = W2; out = W2T; R = DFF; Cn = CC;
        c0 = (i4 % 12) * 32; r0 = (i4 / 12) * 32;
    }
    const int tid = threadIdx.x, tx = tid & 31, ty = tid >> 5;
    #pragma unroll
    for (int p = 0; p < 4; ++p)
        t[ty + p * 8][tx] = in[(long)(r0 + ty + p * 8) * Cn + c0 + tx];
    __syncthreads();
    #pragma unroll
    for (int p = 0; p < 4; ++p)
        out[(long)(c0 + ty + p * 8) * R + r0 + tx] = __float2bfloat16(t[tx][ty + p * 8]);
}

// ---------------- MFMA GEMM 256x128, BK=32, 3-buffer single-barrier phases ----
// C[M,N] = A[M,K] * BT[N,K]^T. 8 waves (2M x 4N), per-wave 128x32.
// BM=256 per the m232 tile-size gate; fine phases (16 MFMA) with ONE barrier:
//   phase(t): WAITV(3)  [own tile-t loads done; tile-t+1's 3 stay in flight]
//             s_barrier [all waves' tile-t loads landed]
//             sched_barrier [no ds_read may hoist above the barrier]
//             ds_read x10 (tile t) ; stage tile t+2 -> buf (t+2)%3
//             setprio(1); 16 MFMA (compiler inserts fine lgkmcnt); setprio(0)
// WAR safety without WAITL: buf (t+2)%3 was read at phase t-1; those reads
// retired before MFMA(t-1) (hw lgkm dep), which precedes this phase's barrier,
// which precedes the stage issue. Counted vmcnt never drains mid-loop.
// LDS = 3 x (16K A + 8K B) = 72 KB. NT % 3 == 0 (K=384 -> 12, K=1536 -> 48).
// EPI: 1 = bias+relu -> bf16; 2 = bias+residual -> fp32; 3 = bf16 store
template<int K, int EPI>
__global__ __launch_bounds__(512) void gemm8(
        const bf16* __restrict__ A, const bf16* __restrict__ BT,
        const float* __restrict__ bias, const float* __restrict__ res,
        float* __restrict__ outF, bf16* __restrict__ outB, int N, int nby) {
    __shared__ bf16 A0[256 * 32];
    __shared__ bf16 A1[256 * 32];
    __shared__ bf16 A2[256 * 32];
    __shared__ bf16 B0[128 * 32];
    __shared__ bf16 B1[128 * 32];
    __shared__ bf16 B2[128 * 32];

    const int tid = threadIdx.x;

    // XCD-chunked block swizzle (grid multiple of 8; all ours are)
    const int hwid  = blockIdx.x;
    const int chunk = gridDim.x >> 3;
    const int e     = hwid & 7;
    const int s     = hwid >> 3;
    const int gx    = chunk / nby;
    const int bx    = e * gx + s / nby;
    const int by    = s - (s / nby) * nby;
    const int m0 = bx * 256;
    const int n0 = by * 128;

    const int ln   = tid & 63;
    const int wid  = tid >> 6;           // 0..7
    const int wm   = (wid & 1) * 128;    // M-half of 256
    const int wn   = (wid >> 1) * 32;    // N-quarter of 128
    const int fr   = ln & 15;
    const int quad = ln >> 4;
    const int slot = quad ^ ((fr >> 1) & 3);

    const bf16* Ap  = A  + (long)m0 * K;
    const bf16* BTp = BT + (long)n0 * K;

    f32x4 acc[8][2];
    #pragma unroll
    for (int i = 0; i < 8; ++i)
        #pragma unroll
        for (int j = 0; j < 2; ++j)
            acc[i][j] = (f32x4){0.f, 0.f, 0.f, 0.f};

    constexpr int NT = K / 32;
    static_assert(NT % 3 == 0, "3-buffer rotation requires NT % 3 == 0");

    // stage one K-tile (3 loads/thread, uniform): A 1024 chunks, B 512 chunks
    auto stageT = [&](long k0, bf16* Ad, bf16* Bd) {
        #pragma unroll
        for (int p = 0; p < 2; ++p) {
            const int u = tid + p * 512;
            const int row = u >> 2;
            const int cc  = (u & 3) ^ ((row >> 1) & 3);
            async_copy16(Ap + (long)row * K + k0 + cc * 8, Ad + u * 8);
        }
        {
            const int u = tid;
            const int row = u >> 2;
            const int cc  = (u & 3) ^ ((row >> 1) & 3);
            async_copy16(BTp + (long)row * K + k0 + cc * 8, Bd + u * 8);
        }
    };

    auto phase = [&](int t, const bf16* Ar, const bf16* Br, bf16* As_, bf16* Bs_) {
        if (t + 1 < NT) { WAITV(3); } else { WAITV(0); }
        BAR;
        SCHED;                                  // nothing hoists above the barrier
        short8 af[8], bfr[2];
        #pragma unroll
        for (int i = 0; i < 8; ++i)
            af[i] = *(const short8*)(Ar + (wm + i * 16 + fr) * 32 + slot * 8);
        #pragma unroll
        for (int j = 0; j < 2; ++j)
            bfr[j] = *(const short8*)(Br + (wn + j * 16 + fr) * 32 + slot * 8);
        if (t + 2 < NT) stageT((long)(t + 2) * 32, As_, Bs_);
        __builtin_amdgcn_s_setprio(1);
        #pragma unroll
        for (int i = 0; i < 8; ++i)
            #pragma unroll
            for (int j = 0; j < 2; ++j)
                acc[i][j] = __builtin_amdgcn_mfma_f32_16x16x32_bf16(
                    af[i], bfr[j], acc[i][j], 0, 0, 0);
        __builtin_amdgcn_s_setprio(0);
    };

    // prologue: tiles 0,1 staged (6 loads/thread in flight)
    stageT(0,  A0, B0);
    stageT(32, A1, B1);

    for (int t = 0; t < NT; t += 3) {
        phase(t,     A0, B0, A2, B2);
        phase(t + 1, A1, B1, A0, B0);
        phase(t + 2, A2, B2, A1, B1);
    }

    #pragma unroll
    for (int i = 0; i < 8; ++i) {
        #pragma unroll
        for (int j = 0; j < 2; ++j) {
            const int col = n0 + wn + j * 16 + fr;
            #pragma unroll
            for (int r = 0; r < 4; ++r) {
                const int row = m0 + wm + i * 16 + quad * 4 + r;
                const long idx = (long)row * N + col;
                float v = acc[i][j][r];
                if (EPI == 1) {
                    v = fmaxf(v + bias[col], 0.f);
                    outB[idx] = __float2bfloat16(v);
                } else if (EPI == 2) {
                    outF[idx] = v + bias[col] + res[idx];
                } else {
                    outB[idx] = __float2bfloat16(v);
                }
            }
        }
    }
}

// ---------------- MFMA causal flash attention ---------------------------------
struct alignas(8) bh4s { bf16 a, b, c, d; };

__global__ __launch_bounds__(256, 2) void attn_mfma_kernel(
        const bf16* __restrict__ qkv, bf16* __restrict__ ab) {
    __shared__ bf16 Kt[64][72];
    __shared__ bf16 Vt[64][72];
    __shared__ bf16 Pb[4][16][72];

    const int tid  = threadIdx.x;
    const int bh   = blockIdx.x;
    const int b    = bh / HH, h = bh % HH;
    const int w    = tid >> 6;
    const int ln   = tid & 63;
    const int ln15 = ln & 15;
    const int quad = ln >> 4;

    short8 qf[4][2];
    #pragma unroll
    for (int i = 0; i < 4; ++i) {
        const long tok = (long)b * TT + w * 16 + i * 64 + ln15;
        const bf16* p = qkv + tok * NQKV + h * HSZ + quad * 8;
        qf[i][0] = *(const short8*)p;
        qf[i][1] = *(const short8*)(p + 32);
    }

    f32x4 accO[4][4];
    float mrow[4][4], lrow[4][4];
    #pragma unroll
    for (int i = 0; i < 4; ++i) {
        #pragma unroll
        for (int j = 0; j < 4; ++j) accO[i][j] = (f32x4){0.f, 0.f, 0.f, 0.f};
        #pragma unroll
        for (int r = 0; r < 4; ++r) { mrow[i][r] = -1e30f; lrow[i][r] = 0.f; }
    }

    for (int sidx = 0; sidx < 4; ++sidx) {
        const int s0 = sidx * 64;
        __syncthreads();
        {
            const bf16* kg = qkv + (long)(b * TT + s0) * NQKV + CC + h * HSZ;
            #pragma unroll
            for (int it = 0; it < 2; ++it) {
                const int u = tid + it * 256;
                const int r = u >> 3, c = (u & 7) * 8;
                *(uint4*)&Kt[r][c] = *(const uint4*)(kg + (long)r * NQKV + c);
            }
            const bf16* vg = qkv + (long)(b * TT + s0) * NQKV + 2 * CC + h * HSZ;
            const int s = tid & 63;
            #pragma unroll
            for (int it = 0; it < 4; ++it) {
                const int dq = (tid >> 6) + it * 4;
                const bh4s vv = *(const bh4s*)(vg + (long)s * NQKV + dq * 4);
                Vt[dq * 4 + 0][s] = vv.a;
                Vt[dq * 4 + 1][s] = vv.b;
                Vt[dq * 4 + 2][s] = vv.c;
                Vt[dq * 4 + 3][s] = vv.d;
            }
        }
        __syncthreads();

        #pragma unroll
        for (int i = 0; i < 4; ++i) {
            if (i < sidx) continue;        // uniform guard; i stays compile-time
            const int rb = w * 16 + i * 64;
            f32x4 S[4];
            #pragma unroll
            for (int jt = 0; jt < 4; ++jt) S[jt] = (f32x4){0.f, 0.f, 0.f, 0.f};
            #pragma unroll
            for (int ks = 0; ks < 2; ++ks) {
                #pragma unroll
                for (int jt = 0; jt < 4; ++jt) {
                    const short8 kf = *(const short8*)&Kt[jt * 16 + ln15][ks * 32 + quad * 8];
                    S[jt] = __builtin_amdgcn_mfma_f32_16x16x32_bf16(qf[i][ks], kf, S[jt], 0, 0, 0);
                }
            }
            float rmax[4];
            #pragma unroll
            for (int r = 0; r < 4; ++r) rmax[r] = -1e30f;
            #pragma unroll
            for (int jt = 0; jt < 4; ++jt) {
                #pragma unroll
                for (int r = 0; r < 4; ++r) {
                    float v = S[jt][r] * 0.125f;
                    if (i == sidx) {
                        const int col = s0 + jt * 16 + ln15;
                        const int row = rb + quad * 4 + r;
                        if (col > row) v = -1e30f;
                    }
                    S[jt][r] = v;
                    rmax[r] = fmaxf(rmax[r], v);
                }
            }
            #pragma unroll
            for (int off = 1; off < 16; off <<= 1)
                #pragma unroll
                for (int r = 0; r < 4; ++r)
                    rmax[r] = fmaxf(rmax[r], __shfl_xor(rmax[r], off, 64));

            float alpha[4], rsum[4];
            #pragma unroll
            for (int r = 0; r < 4; ++r) {
                const float mn = fmaxf(mrow[i][r], rmax[r]);
                alpha[r] = __expf(mrow[i][r] - mn);
                mrow[i][r] = mn;
                rsum[r] = 0.f;
            }
            #pragma unroll
            for (int jt = 0; jt < 4; ++jt)
                #pragma unroll
                for (int r = 0; r < 4; ++r) {
                    const float p = __expf(S[jt][r] - mrow[i][r]);
                    S[jt][r] = p;
                    rsum[r] += p;
                }
            #pragma unroll
            for (int off = 1; off < 16; off <<= 1)
                #pragma unroll
                for (int r = 0; r < 4; ++r)
                    rsum[r] += __shfl_xor(rsum[r], off, 64);
            #pragma unroll
            for (int r = 0; r < 4; ++r)
                lrow[i][r] = lrow[i][r] * alpha[r] + rsum[r];
            #pragma unroll
            for (int jt = 0; jt < 4; ++jt)
                #pragma unroll
                for (int r = 0; r < 4; ++r)
                    accO[i][jt][r] *= alpha[r];

            #pragma unroll
            for (int jt = 0; jt < 4; ++jt)
                #pragma unroll
                for (int r = 0; r < 4; ++r)
                    Pb[w][quad * 4 + r][jt * 16 + ln15] = __float2bfloat16(S[jt][r]);
            const short8 pf0 = *(const short8*)&Pb[w][ln15][quad * 8];
            const short8 pf1 = *(const short8*)&Pb[w][ln15][32 + quad * 8];
            #pragma unroll
            for (int jt = 0; jt < 4; ++jt) {
                const short8 vf0 = *(const short8*)&Vt[jt * 16 + ln15][quad * 8];
                const short8 vf1 = *(const short8*)&Vt[jt * 16 + ln15][32 + quad * 8];
                accO[i][jt] = __builtin_amdgcn_mfma_f32_16x16x32_bf16(pf0, vf0, accO[i][jt], 0, 0, 0);
                accO[i][jt] = __builtin_amdgcn_mfma_f32_16x16x32_bf16(pf1, vf1, accO[i][jt], 0, 0, 0);
            }
        }
    }

    #pragma unroll
    for (int i = 0; i < 4; ++i) {
        const int rb = w * 16 + i * 64;
        float inv[4];
        #pragma unroll
        for (int r = 0; r < 4; ++r) inv[r] = 1.0f / lrow[i][r];
        #pragma unroll
        for (int jt = 0; jt < 4; ++jt)
            #pragma unroll
            for (int r = 0; r < 4; ++r)
                Pb[w][quad * 4 + r][jt * 16 + ln15] = __float2bfloat16(accO[i][jt][r] * inv[r]);
        #pragma unroll
        for (int it = 0; it < 2; ++it) {
            const int u = ln + it * 64;
            const int row = u >> 3, ch = (u & 7) * 8;
            const long tok = (long)b * TT + rb + row;
            *(uint4*)(ab + tok * CC + h * HSZ + ch) = *(const uint4*)&Pb[w][row][ch];
        }
    }
}

// ---------------- launcher ----------------------------------------------------
extern "C" void kernel_launch(void* const* d_in, const int* in_sizes, int n_in,
                              void* d_out, int out_size, void* d_ws, size_t ws_size,
                              hipStream_t stream) {
    const float* x   = (const float*)d_in[0];
    const float* Wq  = (const float*)d_in[1];
    const float* Wk  = (const float*)d_in[2];
    const float* Wv  = (const float*)d_in[3];
    const float* Wo  = (const float*)d_in[4];
    const float* bo  = (const float*)d_in[5];
    const float* W1  = (const float*)d_in[6];
    const float* b1  = (const float*)d_in[7];
    const float* W2  = (const float*)d_in[8];
    const float* b2  = (const float*)d_in[9];
    const float* g1  = (const float*)d_in[10];
    const float* be1 = (const float*)d_in[11];
    const float* g2  = (const float*)d_in[12];
    const float* be2 = (const float*)d_in[13];

    float* out = (float*)d_out;
    char*  ws  = (char*)d_ws;

    const size_t qkvBytes = (size_t)NTOK * NQKV * 4;
    const size_t actOff   = (qkvBytes + 255) & ~(size_t)255;
    const size_t actBytes = (size_t)NTOK * CC * 2;
    size_t wOff = (actOff + actBytes + 255) & ~(size_t)255;

    bf16* qkvb = (bf16*)ws;
    bf16* ff1  = (bf16*)ws;
    bf16* actb = (bf16*)(ws + actOff);

    bf16* WcatT = (bf16*)(ws + wOff); wOff += (size_t)NQKV * CC * 2 + 256;
    bf16* WoT   = (bf16*)(ws + ((wOff + 255) & ~(size_t)255)); wOff = ((wOff + 255) & ~(size_t)255) + (size_t)CC * CC * 2;
    bf16* W1T   = (bf16*)(ws + ((wOff + 255) & ~(size_t)255)); wOff = ((wOff + 255) & ~(size_t)255) + (size_t)DFF * CC * 2;
    bf16* W2T   = (bf16*)(ws + ((wOff + 255) & ~(size_t)255));

    pack_weights<<<1728, 256, 0, stream>>>(Wq, Wk, Wv, Wo, W1, W2,
                                           WcatT, WoT, W1T, W2T);

    ln_bf16_kernel<<<NTOK / RPB, CC, 0, stream>>>(x, g1, be1, actb);
    // QKV: M=32768 (128 row-panels of 256), N=1152 (9 col-tiles) -> 1152 blocks
    gemm8<CC, 3><<<(NTOK / 256) * (NQKV / 128), 512, 0, stream>>>(
        actb, WcatT, nullptr, nullptr, nullptr, qkvb, NQKV, NQKV / 128);
    attn_mfma_kernel<<<BB * HH, 256, 0, stream>>>(qkvb, actb);
    // Wo: N=384 (3 col-tiles) -> 384 blocks
    gemm8<CC, 2><<<(NTOK / 256) * (CC / 128), 512, 0, stream>>>(
        actb, WoT, bo, x, out, nullptr, CC, CC / 128);

    ln_bf16_kernel<<<NTOK / RPB, CC, 0, stream>>>(out, g2, be2, actb);
    // W1: N=1536 (12 col-tiles) -> 1536 blocks
    gemm8<CC, 1><<<(NTOK / 256) * (DFF / 128), 512, 0, stream>>>(
        actb, W1T, b1, nullptr, nullptr, ff1, DFF, DFF / 128);
    // W2: K=1536, N=384 -> 384 blocks
    gemm8<DFF, 2><<<(NTOK / 256) * (CC / 128), 512, 0, stream>>>(
        ff1, W2T, b2, out, out, nullptr, CC, CC / 128);
}